// Round 1
// baseline (163.473 us; speedup 1.0000x reference)
//
#include <hip/hip_runtime.h>
#include <math.h>

#define NB 2
#define LL 4096
#define HH 1024
#define DD 64
#define CHK 64
#define NCH 64            /* LL/CHK */
#define BLROWS (NB*LL)    /* 8192 */
#define GAMMA 0.96875f
#define KB 32

// ---------------------------------------------------------------------------
// Kernel 1: fused projection X@{W_Q,W_K,W_V} + xPos rotation/scale epilogue.
// grid: 8192/32 = 256 blocks, 256 threads.
// thread: rg = tid>>5 (8 rowgroups x 4 rows), cg = tid&31 (32 colgroups x 6 cols
// of the concatenated 192-col [Q|K|V] output).
// ---------------------------------------------------------------------------
__global__ __launch_bounds__(256) void proj_xpos(
    const float* __restrict__ X, const float* __restrict__ WQ,
    const float* __restrict__ WK, const float* __restrict__ WV,
    float* __restrict__ Qx, float* __restrict__ Kx, float* __restrict__ Vx)
{
    __shared__ float Xl[32][36];      // 32 rows x 32 k, padded to 36 for banks
    __shared__ float Wl[KB][192];     // k-chunk x concat cols
    const int tid = threadIdx.x;
    const int rg  = tid >> 5;
    const int cg  = tid & 31;
    const int r0  = blockIdx.x * 32;
    const int c0  = cg * 6;

    float acc[4][6];
#pragma unroll
    for (int r = 0; r < 4; ++r)
#pragma unroll
        for (int j = 0; j < 6; ++j) acc[r][j] = 0.f;

    for (int k0 = 0; k0 < HH; k0 += KB) {
        __syncthreads();
        // stage X tile (1024 floats, 1 float4/thread)
        {
            const int row = tid >> 3;
            const int c4  = (tid & 7) * 4;
            const float4 xv = *(const float4*)&X[(size_t)(r0 + row) * HH + k0 + c4];
            *(float4*)&Xl[row][c4] = xv;
        }
        // stage W tiles (3*32*64 = 6144 floats, 6 float4/thread)
#pragma unroll
        for (int i = 0; i < 6; ++i) {
            const int f   = tid + i * 256;      // 0..1535
            const int mat = f >> 9;             // 0..2
            const int rem = f & 511;
            const int kk  = rem >> 4;           // 0..31
            const int c4  = (rem & 15) * 4;     // 0..60
            const float* Wsrc = (mat == 0) ? WQ : (mat == 1) ? WK : WV;
            const float4 wv = *(const float4*)&Wsrc[(size_t)(k0 + kk) * DD + c4];
            *(float4*)&Wl[kk][mat * 64 + c4] = wv;
        }
        __syncthreads();
#pragma unroll
        for (int k4 = 0; k4 < KB / 4; ++k4) {
            float4 xq[4];
#pragma unroll
            for (int r = 0; r < 4; ++r)
                xq[r] = *(const float4*)&Xl[rg * 4 + r][k4 * 4];
#pragma unroll
            for (int u = 0; u < 4; ++u) {
                const int kk = k4 * 4 + u;
                const float2 w0 = *(const float2*)&Wl[kk][c0];
                const float2 w1 = *(const float2*)&Wl[kk][c0 + 2];
                const float2 w2 = *(const float2*)&Wl[kk][c0 + 4];
#pragma unroll
                for (int r = 0; r < 4; ++r) {
                    const float x = (u == 0) ? xq[r].x : (u == 1) ? xq[r].y
                                  : (u == 2) ? xq[r].z : xq[r].w;
                    acc[r][0] += x * w0.x; acc[r][1] += x * w0.y;
                    acc[r][2] += x * w1.x; acc[r][3] += x * w1.y;
                    acc[r][4] += x * w2.x; acc[r][5] += x * w2.y;
                }
            }
        }
    }
    // epilogue: xPos rotate+scale for Q/K columns; passthrough for V.
#pragma unroll
    for (int p = 0; p < 6; p += 2) {
        const int cc = c0 + p;   // even → rotation pairs never split
        if (cc < 128) {
            const int d = cc & 63;
            const int i = d >> 1;
            const float sv   = (2.f * (float)i + 0.4f * 64.f) / (1.4f * 64.f);
            const float l2sv = log2f(sv);
            // inv_freq = 10000^(-i/32);  log2(10000)=13.28771237954945
            const float ifr  = exp2f(-13.28771237954945f * ((float)i / 32.f));
            const float sgn  = (cc < 64) ? 1.f : -1.f;   // K is downscaled
            float* base = (cc < 64) ? Qx : Kx;
#pragma unroll
            for (int r = 0; r < 4; ++r) {
                const int row = r0 + rg * 4 + r;
                const float pf = (float)(row & (LL - 1));
                const float scl = exp2f(sgn * (pf * (1.f / 512.f)) * l2sv);
                float s, c;
                sincosf(pf * ifr, &s, &c);
                s *= scl; c *= scl;
                const float x0 = acc[r][p], x1 = acc[r][p + 1];
                const float2 y = make_float2(x0 * c - x1 * s, x1 * c + x0 * s);
                *(float2*)&base[(size_t)row * DD + d] = y;
            }
        } else {
            const int d = cc - 128;
#pragma unroll
            for (int r = 0; r < 4; ++r) {
                const int row = r0 + rg * 4 + r;
                *(float2*)&Vx[(size_t)row * DD + d] =
                    make_float2(acc[r][p], acc[r][p + 1]);
            }
        }
    }
}

// ---------------------------------------------------------------------------
// Kernel 2: per-chunk KV summary  U_c[d][d'] = sum_j gamma^(63-j) K[j][d] V[j][d']
// grid: NB*NCH = 128 blocks, 256 threads.
// ---------------------------------------------------------------------------
__global__ __launch_bounds__(256) void chunk_kv(
    const float* __restrict__ Kx, const float* __restrict__ Vx,
    float* __restrict__ U)
{
    __shared__ float Kl[CHK][DD];
    __shared__ float Vl[CHK][DD];
    const int tid = threadIdx.x;
    const int bc  = blockIdx.x;
    const size_t base = (size_t)bc * CHK * DD;
    const float l2g = log2f(GAMMA);
#pragma unroll
    for (int i = 0; i < 4; ++i) {
        const int f   = tid + i * 256;
        const int row = f >> 4;
        const int c4  = (f & 15) * 4;
        float4 kv = *(const float4*)&Kx[base + (size_t)row * DD + c4];
        const float w = exp2f((float)(CHK - 1 - row) * l2g);
        kv.x *= w; kv.y *= w; kv.z *= w; kv.w *= w;
        *(float4*)&Kl[row][c4] = kv;
        *(float4*)&Vl[row][c4] = *(const float4*)&Vx[base + (size_t)row * DD + c4];
    }
    __syncthreads();
    const int dgr = tid >> 4;   // 16 groups x 4 d-rows
    const int dc  = tid & 15;   // float4 group of d'
    float a0[4] = {0,0,0,0}, a1[4] = {0,0,0,0}, a2[4] = {0,0,0,0}, a3[4] = {0,0,0,0};
#pragma unroll 8
    for (int j = 0; j < CHK; ++j) {
        const float4 kv = *(const float4*)&Kl[j][dgr * 4];
        const float4 vv = *(const float4*)&Vl[j][dc * 4];
        a0[0] += kv.x * vv.x; a0[1] += kv.x * vv.y; a0[2] += kv.x * vv.z; a0[3] += kv.x * vv.w;
        a1[0] += kv.y * vv.x; a1[1] += kv.y * vv.y; a1[2] += kv.y * vv.z; a1[3] += kv.y * vv.w;
        a2[0] += kv.z * vv.x; a2[1] += kv.z * vv.y; a2[2] += kv.z * vv.z; a2[3] += kv.z * vv.w;
        a3[0] += kv.w * vv.x; a3[1] += kv.w * vv.y; a3[2] += kv.w * vv.z; a3[3] += kv.w * vv.w;
    }
    float* dst = &U[base];
    *(float4*)&dst[(dgr * 4 + 0) * DD + dc * 4] = make_float4(a0[0], a0[1], a0[2], a0[3]);
    *(float4*)&dst[(dgr * 4 + 1) * DD + dc * 4] = make_float4(a1[0], a1[1], a1[2], a1[3]);
    *(float4*)&dst[(dgr * 4 + 2) * DD + dc * 4] = make_float4(a2[0], a2[1], a2[2], a2[3]);
    *(float4*)&dst[(dgr * 4 + 3) * DD + dc * 4] = make_float4(a3[0], a3[1], a3[2], a3[3]);
}

// ---------------------------------------------------------------------------
// Kernel 3: scan  T_0 = 0 ; T_c = gamma^64 * T_{c-1} + U_{c-1}
// grid: NB*DD = 128 blocks, 64 threads (thread = d').
// ---------------------------------------------------------------------------
__global__ __launch_bounds__(64) void scan_kv(
    const float* __restrict__ U, float* __restrict__ T)
{
    const int bd = blockIdx.x;          // b*64 + d
    const int b  = bd >> 6;
    const int d  = bd & 63;
    const int dp = threadIdx.x;
    const float g64 = exp2f(64.f * log2f(GAMMA));
    float t = 0.f;
#pragma unroll
    for (int c = 0; c < NCH; ++c) {
        const size_t idx = ((size_t)(b * NCH + c) * DD + d) * DD + dp;
        T[idx] = t;
        t = t * g64 + U[idx];
    }
}

// ---------------------------------------------------------------------------
// Kernel 4: per-chunk output.
//   S[n][m] = (Q_n . K_m) * gamma^(n-m) * (n>=m)           (intra-chunk)
//   augmented: S2[n][64+d] = gamma^(n+1) * Q[n][d]          (cross-chunk)
//   out[n][d'] = sum_{m<128} S2[n][m] * VT[m][d'],  VT = [V ; T_c]
// grid: NB*NCH = 128 blocks, 256 threads.
// ---------------------------------------------------------------------------
__global__ __launch_bounds__(256) void chunk_out(
    const float* __restrict__ Qx, const float* __restrict__ Kx,
    const float* __restrict__ Vx, const float* __restrict__ T,
    float* __restrict__ out)
{
    __shared__ float Ql[CHK][DD];        // 16 KB
    __shared__ float Klt[DD][CHK];       // K transposed [k][m], 16 KB
    __shared__ float VT[2 * DD][DD];     // [V ; T], 32 KB
    __shared__ float S2[CHK][2 * DD];    // augmented scores, 32 KB
    __shared__ float pwl[CHK + 1];
    const int tid = threadIdx.x;
    const int bc  = blockIdx.x;
    const size_t base = (size_t)bc * CHK * DD;

    if (tid <= CHK) pwl[tid] = exp2f((float)tid * log2f(GAMMA));

#pragma unroll
    for (int i = 0; i < 4; ++i) {
        const int f   = tid + i * 256;
        const int row = f >> 4;
        const int c4  = (f & 15) * 4;
        *(float4*)&Ql[row][c4]      = *(const float4*)&Qx[base + (size_t)row * DD + c4];
        *(float4*)&VT[row][c4]      = *(const float4*)&Vx[base + (size_t)row * DD + c4];
        *(float4*)&VT[64 + row][c4] = *(const float4*)&T[base + (size_t)row * DD + c4];
        // K transposed staging: column strip (conflict-free LDS stores)
        const int m  = f & 63;
        const int k4 = (f >> 6) * 4;
        const float4 kk = *(const float4*)&Kx[base + (size_t)m * DD + k4];
        Klt[k4 + 0][m] = kk.x; Klt[k4 + 1][m] = kk.y;
        Klt[k4 + 2][m] = kk.z; Klt[k4 + 3][m] = kk.w;
    }
    __syncthreads();

    // ---- phase 1: scores (64x64x64 GEMM), thread tile 4n x 4m ----
    const int ng = tid >> 4;
    const int mg = tid & 15;
    float sacc[4][4];
#pragma unroll
    for (int r = 0; r < 4; ++r)
#pragma unroll
        for (int q = 0; q < 4; ++q) sacc[r][q] = 0.f;

#pragma unroll 4
    for (int k4 = 0; k4 < 16; ++k4) {
        float4 qv[4];
#pragma unroll
        for (int r = 0; r < 4; ++r)
            qv[r] = *(const float4*)&Ql[ng * 4 + r][k4 * 4];
#pragma unroll
        for (int u = 0; u < 4; ++u) {
            const float4 kv = *(const float4*)&Klt[k4 * 4 + u][mg * 4];
#pragma unroll
            for (int r = 0; r < 4; ++r) {
                const float q = (u == 0) ? qv[r].x : (u == 1) ? qv[r].y
                              : (u == 2) ? qv[r].z : qv[r].w;
                sacc[r][0] += q * kv.x; sacc[r][1] += q * kv.y;
                sacc[r][2] += q * kv.z; sacc[r][3] += q * kv.w;
            }
        }
    }
#pragma unroll
    for (int r = 0; r < 4; ++r) {
        const int n = ng * 4 + r;
        float4 sv;
        const int m0 = mg * 4;
        sv.x = (n >= m0 + 0) ? sacc[r][0] * pwl[n - (m0 + 0)] : 0.f;
        sv.y = (n >= m0 + 1) ? sacc[r][1] * pwl[n - (m0 + 1)] : 0.f;
        sv.z = (n >= m0 + 2) ? sacc[r][2] * pwl[n - (m0 + 2)] : 0.f;
        sv.w = (n >= m0 + 3) ? sacc[r][3] * pwl[n - (m0 + 3)] : 0.f;
        *(float4*)&S2[n][m0] = sv;
        float4 qv = *(const float4*)&Ql[n][m0];
        const float w = pwl[n + 1];
        qv.x *= w; qv.y *= w; qv.z *= w; qv.w *= w;
        *(float4*)&S2[n][64 + m0] = qv;
    }
    __syncthreads();

    // ---- phase 2: out = S2 @ VT  (64x64x128), thread tile 4n x 4d' ----
    const int dg = tid & 15;
    float oacc[4][4];
#pragma unroll
    for (int r = 0; r < 4; ++r)
#pragma unroll
        for (int q = 0; q < 4; ++q) oacc[r][q] = 0.f;

#pragma unroll 4
    for (int m4 = 0; m4 < 32; ++m4) {
        float4 sv[4];
#pragma unroll
        for (int r = 0; r < 4; ++r)
            sv[r] = *(const float4*)&S2[ng * 4 + r][m4 * 4];
#pragma unroll
        for (int mm = 0; mm < 4; ++mm) {
            const float4 vv = *(const float4*)&VT[m4 * 4 + mm][dg * 4];
#pragma unroll
            for (int r = 0; r < 4; ++r) {
                const float s = (mm == 0) ? sv[r].x : (mm == 1) ? sv[r].y
                              : (mm == 2) ? sv[r].z : sv[r].w;
                oacc[r][0] += s * vv.x; oacc[r][1] += s * vv.y;
                oacc[r][2] += s * vv.z; oacc[r][3] += s * vv.w;
            }
        }
    }
#pragma unroll
    for (int r = 0; r < 4; ++r) {
        *(float4*)&out[base + (size_t)(ng * 4 + r) * DD + dg * 4] =
            make_float4(oacc[r][0], oacc[r][1], oacc[r][2], oacc[r][3]);
    }
}

// ---------------------------------------------------------------------------
extern "C" void kernel_launch(void* const* d_in, const int* in_sizes, int n_in,
                              void* d_out, int out_size, void* d_ws, size_t ws_size,
                              hipStream_t stream)
{
    const float* X  = (const float*)d_in[0];
    const float* WQ = (const float*)d_in[1];
    const float* WK = (const float*)d_in[2];
    const float* WV = (const float*)d_in[3];
    float* out = (float*)d_out;

    float* ws = (float*)d_ws;
    float* Qx = ws;                                    // 8192*64
    float* Kx = Qx + (size_t)BLROWS * DD;              // 8192*64
    float* Vx = Kx + (size_t)BLROWS * DD;              // 8192*64
    float* U  = Vx + (size_t)BLROWS * DD;              // 2*64*64*64
    float* T  = U  + (size_t)NB * NCH * DD * DD;       // 2*64*64*64
    // total ws use: 5 * 524288 floats = 10.5 MB

    hipLaunchKernelGGL(proj_xpos, dim3(BLROWS / 32), dim3(256), 0, stream,
                       X, WQ, WK, WV, Qx, Kx, Vx);
    hipLaunchKernelGGL(chunk_kv, dim3(NB * NCH), dim3(256), 0, stream, Kx, Vx, U);
    hipLaunchKernelGGL(scan_kv, dim3(NB * DD), dim3(64), 0, stream, U, T);
    hipLaunchKernelGGL(chunk_out, dim3(NB * NCH), dim3(256), 0, stream,
                       Qx, Kx, Vx, T, out);
}

// Round 2
// 136.096 us; speedup vs baseline: 1.2012x; 1.2012x over previous
//
#include <hip/hip_runtime.h>
#include <math.h>

#define NB 2
#define LL 4096
#define HH 1024
#define DD 64
#define CHK 64
#define NCH 64            /* LL/CHK */
#define BLROWS (NB*LL)    /* 8192 */
#define GAMMA 0.96875f
#define KB 16
#define NSPLIT 4
#define KSPAN (HH/NSPLIT)   /* 256 */
#define NKCH (KSPAN/KB)     /* 16 chunks per split */

// ---------------------------------------------------------------------------
// Kernel 1: fused projection + xPos, in-block 4-way split-K.
// grid 256 blocks x 1024 threads (16 waves/CU). Quarter q = tid>>8 owns
// K range [q*256, q*256+256) staged in its own LDS slice (KB=16 chunks),
// register-prefetch pipelined. Cross-quarter reduce via LDS, epilogue on q==0.
// LDS: 4 * (Xl[32][20] + Wl[16][192]) = 59392 B.
// ---------------------------------------------------------------------------
__global__ __launch_bounds__(1024) void proj_xpos(
    const float* __restrict__ X, const float* __restrict__ WQ,
    const float* __restrict__ WK, const float* __restrict__ WV,
    float* __restrict__ Qx, float* __restrict__ Kx, float* __restrict__ Vx)
{
    __shared__ __align__(16) float smem[4 * 3712];   // per-quarter: Xl 640 + Wl 3072
    const int tid = threadIdx.x;
    const int q   = tid >> 8;
    const int t   = tid & 255;
    const int rg  = t >> 5;
    const int cg  = t & 31;
    const int r0  = blockIdx.x * 32;
    const int c0  = cg * 6;
    const int qb  = q * 3712;

    // fixed staging coordinates
    const int xrow = t >> 3;             // 0..31
    const int xc2  = (t & 7) * 2;        // 0..14
    const int wkk  = t >> 4;             // 0..15
    const int wc4  = (t & 15) * 4;       // 0..60

    float accf[24];
#pragma unroll
    for (int i = 0; i < 24; ++i) accf[i] = 0.f;

    // prefetch chunk 0
    float2 px;
    float4 pw0, pw1, pw2;
    {
        const int k0 = q * KSPAN;
        px  = *(const float2*)&X[(size_t)(r0 + xrow) * HH + k0 + xc2];
        pw0 = *(const float4*)&WQ[(size_t)(k0 + wkk) * DD + wc4];
        pw1 = *(const float4*)&WK[(size_t)(k0 + wkk) * DD + wc4];
        pw2 = *(const float4*)&WV[(size_t)(k0 + wkk) * DD + wc4];
    }

    for (int cc = 0; cc < NKCH; ++cc) {
        __syncthreads();
        // commit prefetched chunk to LDS
        smem[qb + xrow * 20 + xc2]     = px.x;
        smem[qb + xrow * 20 + xc2 + 1] = px.y;
        *(float4*)&smem[qb + 640 + wkk * 192 +   0 + wc4] = pw0;
        *(float4*)&smem[qb + 640 + wkk * 192 +  64 + wc4] = pw1;
        *(float4*)&smem[qb + 640 + wkk * 192 + 128 + wc4] = pw2;
        __syncthreads();
        // prefetch next chunk (overlaps with compute below)
        if (cc + 1 < NKCH) {
            const int k0 = q * KSPAN + (cc + 1) * KB;
            px  = *(const float2*)&X[(size_t)(r0 + xrow) * HH + k0 + xc2];
            pw0 = *(const float4*)&WQ[(size_t)(k0 + wkk) * DD + wc4];
            pw1 = *(const float4*)&WK[(size_t)(k0 + wkk) * DD + wc4];
            pw2 = *(const float4*)&WV[(size_t)(k0 + wkk) * DD + wc4];
        }
#pragma unroll
        for (int k4 = 0; k4 < KB / 4; ++k4) {
            float4 xq[4];
#pragma unroll
            for (int r = 0; r < 4; ++r)
                xq[r] = *(const float4*)&smem[qb + (rg * 4 + r) * 20 + k4 * 4];
#pragma unroll
            for (int u = 0; u < 4; ++u) {
                const int kk = k4 * 4 + u;
                const float* wp = &smem[qb + 640 + kk * 192 + c0];
                const float2 w0 = *(const float2*)&wp[0];
                const float2 w1 = *(const float2*)&wp[2];
                const float2 w2 = *(const float2*)&wp[4];
#pragma unroll
                for (int r = 0; r < 4; ++r) {
                    const float x = (u == 0) ? xq[r].x : (u == 1) ? xq[r].y
                                  : (u == 2) ? xq[r].z : xq[r].w;
                    accf[r * 6 + 0] += x * w0.x; accf[r * 6 + 1] += x * w0.y;
                    accf[r * 6 + 2] += x * w1.x; accf[r * 6 + 3] += x * w1.y;
                    accf[r * 6 + 4] += x * w2.x; accf[r * 6 + 5] += x * w2.y;
                }
            }
        }
    }

    // ---- cross-quarter reduction (transposed scratch: conflict-free) ----
    __syncthreads();
    if (q >= 2) {
#pragma unroll
        for (int i = 0; i < 24; ++i) smem[i * 512 + (q - 2) * 256 + t] = accf[i];
    }
    __syncthreads();
    if (q < 2) {
#pragma unroll
        for (int i = 0; i < 24; ++i) accf[i] += smem[i * 512 + q * 256 + t];
    }
    __syncthreads();
    if (q == 1) {
#pragma unroll
        for (int i = 0; i < 24; ++i) smem[i * 256 + t] = accf[i];
    }
    __syncthreads();
    if (q == 0) {
#pragma unroll
        for (int i = 0; i < 24; ++i) accf[i] += smem[i * 256 + t];
        // ---- xPos epilogue ----
#pragma unroll
        for (int p = 0; p < 6; p += 2) {
            const int cc2 = c0 + p;   // even → rotation pairs never split
            if (cc2 < 128) {
                const int d = cc2 & 63;
                const int i = d >> 1;
                const float sv   = (2.f * (float)i + 0.4f * 64.f) / (1.4f * 64.f);
                const float l2sv = log2f(sv);
                const float ifr  = exp2f(-13.28771237954945f * ((float)i / 32.f));
                const float sgn  = (cc2 < 64) ? 1.f : -1.f;
                float* base = (cc2 < 64) ? Qx : Kx;
#pragma unroll
                for (int r = 0; r < 4; ++r) {
                    const int row = r0 + rg * 4 + r;
                    const float pf = (float)(row & (LL - 1));
                    const float scl = exp2f(sgn * (pf * (1.f / 512.f)) * l2sv);
                    float s, c;
                    sincosf(pf * ifr, &s, &c);
                    s *= scl; c *= scl;
                    const float x0 = accf[r * 6 + p], x1 = accf[r * 6 + p + 1];
                    const float2 y = make_float2(x0 * c - x1 * s, x1 * c + x0 * s);
                    *(float2*)&base[(size_t)row * DD + d] = y;
                }
            } else {
                const int d = cc2 - 128;
#pragma unroll
                for (int r = 0; r < 4; ++r) {
                    const int row = r0 + rg * 4 + r;
                    *(float2*)&Vx[(size_t)row * DD + d] =
                        make_float2(accf[r * 6 + p], accf[r * 6 + p + 1]);
                }
            }
        }
    }
}

// ---------------------------------------------------------------------------
// Kernel 2: per-chunk KV summary U[chunk][d][d'] = sum_j g^(63-j) K[j][d] V[j][d']
// grid 256 blocks (chunk x d-half), 256 threads.
// ---------------------------------------------------------------------------
__global__ __launch_bounds__(256) void chunk_kv(
    const float* __restrict__ Kx, const float* __restrict__ Vx,
    float* __restrict__ U)
{
    __shared__ float Kl[CHK][32];
    __shared__ float Vl[CHK][DD];
    const int tid   = threadIdx.x;
    const int bc    = blockIdx.x;
    const int chunk = bc >> 1;
    const int dh    = (bc & 1) * 32;
    const size_t base = (size_t)chunk * CHK * DD;
    const float l2g = log2f(GAMMA);
#pragma unroll
    for (int i = 0; i < 2; ++i) {
        const int f   = tid + i * 256;     // 0..511
        const int row = f >> 3;
        const int c4  = (f & 7) * 4;
        float4 kv = *(const float4*)&Kx[base + (size_t)row * DD + dh + c4];
        const float w = exp2f((float)(CHK - 1 - row) * l2g);
        kv.x *= w; kv.y *= w; kv.z *= w; kv.w *= w;
        *(float4*)&Kl[row][c4] = kv;
    }
#pragma unroll
    for (int i = 0; i < 4; ++i) {
        const int f   = tid + i * 256;
        const int row = f >> 4;
        const int c4  = (f & 15) * 4;
        *(float4*)&Vl[row][c4] = *(const float4*)&Vx[base + (size_t)row * DD + c4];
    }
    __syncthreads();
    const int dgr = tid >> 4;   // 0..15 → 2 d-rows each
    const int dc  = tid & 15;
    float a0[4] = {0,0,0,0}, a1[4] = {0,0,0,0};
#pragma unroll 8
    for (int j = 0; j < CHK; ++j) {
        const float2 kv = *(const float2*)&Kl[j][dgr * 2];
        const float4 vv = *(const float4*)&Vl[j][dc * 4];
        a0[0] += kv.x * vv.x; a0[1] += kv.x * vv.y; a0[2] += kv.x * vv.z; a0[3] += kv.x * vv.w;
        a1[0] += kv.y * vv.x; a1[1] += kv.y * vv.y; a1[2] += kv.y * vv.z; a1[3] += kv.y * vv.w;
    }
    const int d0 = dh + dgr * 2;
    *(float4*)&U[((size_t)chunk * DD + d0 + 0) * DD + dc * 4] = make_float4(a0[0], a0[1], a0[2], a0[3]);
    *(float4*)&U[((size_t)chunk * DD + d0 + 1) * DD + dc * 4] = make_float4(a1[0], a1[1], a1[2], a1[3]);
}

// ---------------------------------------------------------------------------
// Kernel 3: scan  T_0 = 0 ; T_c = gamma^64 * T_{c-1} + U_{c-1}   (per batch)
// grid NB*DD = 128 blocks, 64 threads (thread = d').
// ---------------------------------------------------------------------------
__global__ __launch_bounds__(64) void scan_kv(
    const float* __restrict__ U, float* __restrict__ T)
{
    const int bd = blockIdx.x;          // b*64 + d
    const int b  = bd >> 6;
    const int d  = bd & 63;
    const int dp = threadIdx.x;
    const float g64 = exp2f(64.f * log2f(GAMMA));
    float t = 0.f;
#pragma unroll
    for (int c = 0; c < NCH; ++c) {
        const size_t idx = ((size_t)(b * NCH + c) * DD + d) * DD + dp;
        T[idx] = t;
        t = t * g64 + U[idx];
    }
}

// ---------------------------------------------------------------------------
// Kernel 4: per-chunk output, split by n-half. grid 256 blocks x 256 thr.
//   S[n][m] = (Q_n.K_m) g^(n-m) (n>=m);  S2[n][64+d] = g^(n+1) Q[n][d]
//   out[n] = S2[n] @ [V ; T_c]
// LDS: smA 25088 B (Ql[32][68]+Klt[64][64], aliased by S2[32][132]) +
//      VTl 32768 B + pwl → 58 KB.
// ---------------------------------------------------------------------------
__global__ __launch_bounds__(256) void chunk_out(
    const float* __restrict__ Qx, const float* __restrict__ Kx,
    const float* __restrict__ Vx, const float* __restrict__ T,
    float* __restrict__ out)
{
    __shared__ __align__(16) float smA[6272];       // Ql:0..2175, Klt:2176..6271
    __shared__ __align__(16) float VTl[128 * 64];
    __shared__ float pwl[CHK + 1];
    const int tid   = threadIdx.x;
    const int bc    = blockIdx.x;
    const int chunk = bc >> 1;
    const int nh    = (bc & 1) * 32;
    const size_t base = (size_t)chunk * CHK * DD;

    if (tid <= CHK) pwl[tid] = exp2f((float)tid * log2f(GAMMA));

#pragma unroll
    for (int i = 0; i < 2; ++i) {                   // Ql rows nh..nh+31
        const int f   = tid + i * 256;
        const int row = f >> 4;
        const int c4  = (f & 15) * 4;
        *(float4*)&smA[row * 68 + c4] =
            *(const float4*)&Qx[base + (size_t)(nh + row) * DD + c4];
    }
#pragma unroll
    for (int i = 0; i < 4; ++i) {                   // Klt[k][m]
        const int f  = tid + i * 256;
        const int m  = f & 63;
        const int k4 = (f >> 6) * 4;
        const float4 kk = *(const float4*)&Kx[base + (size_t)m * DD + k4];
        smA[2176 + (k4 + 0) * 64 + m] = kk.x;
        smA[2176 + (k4 + 1) * 64 + m] = kk.y;
        smA[2176 + (k4 + 2) * 64 + m] = kk.z;
        smA[2176 + (k4 + 3) * 64 + m] = kk.w;
    }
#pragma unroll
    for (int i = 0; i < 8; ++i) {                   // VT = [V ; T]
        const int f   = tid + i * 256;
        const int row = f >> 4;
        const int c4  = (f & 15) * 4;
        const float* src = (row < 64)
            ? &Vx[base + (size_t)row * DD + c4]
            : &T[base + (size_t)(row - 64) * DD + c4];
        *(float4*)&VTl[row * 64 + c4] = *(const float4*)src;
    }
    __syncthreads();

    // ---- phase 1: scores, thread tile 2n x 4m ----
    const int ng = tid >> 4;       // 0..15 → rows ng*2+{0,1}
    const int mg = tid & 15;
    const int m0 = mg * 4;
    float sacc[2][4];
#pragma unroll
    for (int r = 0; r < 2; ++r)
#pragma unroll
        for (int j = 0; j < 4; ++j) sacc[r][j] = 0.f;

#pragma unroll 4
    for (int k4 = 0; k4 < 16; ++k4) {
        const float4 qv0 = *(const float4*)&smA[(ng * 2 + 0) * 68 + k4 * 4];
        const float4 qv1 = *(const float4*)&smA[(ng * 2 + 1) * 68 + k4 * 4];
#pragma unroll
        for (int u = 0; u < 4; ++u) {
            const float4 kv = *(const float4*)&smA[2176 + (k4 * 4 + u) * 64 + m0];
            const float x0 = (u == 0) ? qv0.x : (u == 1) ? qv0.y : (u == 2) ? qv0.z : qv0.w;
            const float x1 = (u == 0) ? qv1.x : (u == 1) ? qv1.y : (u == 2) ? qv1.z : qv1.w;
            sacc[0][0] += x0 * kv.x; sacc[0][1] += x0 * kv.y; sacc[0][2] += x0 * kv.z; sacc[0][3] += x0 * kv.w;
            sacc[1][0] += x1 * kv.x; sacc[1][1] += x1 * kv.y; sacc[1][2] += x1 * kv.z; sacc[1][3] += x1 * kv.w;
        }
    }
    // grab aug Q values before smA is overwritten
    const float4 qa0 = *(const float4*)&smA[(ng * 2 + 0) * 68 + m0];
    const float4 qa1 = *(const float4*)&smA[(ng * 2 + 1) * 68 + m0];
    __syncthreads();

    // ---- write S2 (aliases Ql/Klt region) ----
#pragma unroll
    for (int r = 0; r < 2; ++r) {
        const int nl = ng * 2 + r;
        const int n  = nh + nl;
        float4 sv;
        sv.x = (n >= m0 + 0) ? sacc[r][0] * pwl[n - (m0 + 0)] : 0.f;
        sv.y = (n >= m0 + 1) ? sacc[r][1] * pwl[n - (m0 + 1)] : 0.f;
        sv.z = (n >= m0 + 2) ? sacc[r][2] * pwl[n - (m0 + 2)] : 0.f;
        sv.w = (n >= m0 + 3) ? sacc[r][3] * pwl[n - (m0 + 3)] : 0.f;
        *(float4*)&smA[nl * 132 + m0] = sv;
        const float w = pwl[n + 1];
        const float4 qa = r ? qa1 : qa0;
        *(float4*)&smA[nl * 132 + 64 + m0] =
            make_float4(qa.x * w, qa.y * w, qa.z * w, qa.w * w);
    }
    __syncthreads();

    // ---- phase 2: out = S2 @ VT, thread tile 2n x 4d' ----
    const int dg = tid & 15;
    float oacc[2][4];
#pragma unroll
    for (int r = 0; r < 2; ++r)
#pragma unroll
        for (int j = 0; j < 4; ++j) oacc[r][j] = 0.f;

#pragma unroll 4
    for (int m4 = 0; m4 < 32; ++m4) {
        const float4 s0 = *(const float4*)&smA[(ng * 2 + 0) * 132 + m4 * 4];
        const float4 s1 = *(const float4*)&smA[(ng * 2 + 1) * 132 + m4 * 4];
#pragma unroll
        for (int mm = 0; mm < 4; ++mm) {
            const float4 vv = *(const float4*)&VTl[(m4 * 4 + mm) * 64 + dg * 4];
            const float a0 = (mm == 0) ? s0.x : (mm == 1) ? s0.y : (mm == 2) ? s0.z : s0.w;
            const float a1 = (mm == 0) ? s1.x : (mm == 1) ? s1.y : (mm == 2) ? s1.z : s1.w;
            oacc[0][0] += a0 * vv.x; oacc[0][1] += a0 * vv.y; oacc[0][2] += a0 * vv.z; oacc[0][3] += a0 * vv.w;
            oacc[1][0] += a1 * vv.x; oacc[1][1] += a1 * vv.y; oacc[1][2] += a1 * vv.z; oacc[1][3] += a1 * vv.w;
        }
    }
#pragma unroll
    for (int r = 0; r < 2; ++r) {
        *(float4*)&out[base + (size_t)(nh + ng * 2 + r) * DD + dg * 4] =
            make_float4(oacc[r][0], oacc[r][1], oacc[r][2], oacc[r][3]);
    }
}

// ---------------------------------------------------------------------------
extern "C" void kernel_launch(void* const* d_in, const int* in_sizes, int n_in,
                              void* d_out, int out_size, void* d_ws, size_t ws_size,
                              hipStream_t stream)
{
    const float* X  = (const float*)d_in[0];
    const float* WQ = (const float*)d_in[1];
    const float* WK = (const float*)d_in[2];
    const float* WV = (const float*)d_in[3];
    float* out = (float*)d_out;

    float* ws = (float*)d_ws;
    float* Qx = ws;                                    // 8192*64
    float* Kx = Qx + (size_t)BLROWS * DD;              // 8192*64
    float* Vx = Kx + (size_t)BLROWS * DD;              // 8192*64
    float* U  = Vx + (size_t)BLROWS * DD;              // 2*64*64*64
    float* T  = U  + (size_t)NB * NCH * DD * DD;       // 2*64*64*64
    // total ws use: 5 * 524288 floats = 10.5 MB

    hipLaunchKernelGGL(proj_xpos, dim3(BLROWS / 32), dim3(1024), 0, stream,
                       X, WQ, WK, WV, Qx, Kx, Vx);
    hipLaunchKernelGGL(chunk_kv, dim3(2 * NB * NCH), dim3(256), 0, stream, Kx, Vx, U);
    hipLaunchKernelGGL(scan_kv, dim3(NB * DD), dim3(64), 0, stream, U, T);
    hipLaunchKernelGGL(chunk_out, dim3(2 * NB * NCH), dim3(256), 0, stream,
                       Qx, Kx, Vx, T, out);
}

// Round 3
// 124.278 us; speedup vs baseline: 1.3154x; 1.0951x over previous
//
#include <hip/hip_runtime.h>
#include <math.h>

#define NB 2
#define LL 4096
#define HH 1024
#define DD 64
#define CHK 64
#define NCH 64            /* LL/CHK */
#define BLROWS (NB*LL)    /* 8192 */
#define GAMMA 0.96875f

typedef _Float16 f16x8 __attribute__((ext_vector_type(8)));
typedef float    f32x4 __attribute__((ext_vector_type(4)));

// W split layout: [16 kchunks][12 coltiles][2 ktiles][64 lanes][8 halfs]
// chunk stride = 12*2*64*8 = 12288 halfs (24 KB). Frag read = contiguous 16B/lane.
#define WCH 12288

// ---------------------------------------------------------------------------
// Kernel 0: split W (scaled by 2^10) into fp16 hi/lo, fragment-order layout.
// grid 192 x 256. g indexes (matrix m, k, d4-group).
// ---------------------------------------------------------------------------
__global__ __launch_bounds__(256) void prep_w(
    const float* __restrict__ WQ, const float* __restrict__ WK,
    const float* __restrict__ WV, _Float16* __restrict__ Whg,
    _Float16* __restrict__ Wlg)
{
    const int g  = blockIdx.x * 256 + threadIdx.x;   // 0..49151
    const int m  = g >> 14;                          // 0..2
    const int km = g & 16383;
    const int k  = km >> 4;                          // 0..1023
    const int d4 = (km & 15) * 4;                    // 0..60
    const float* Wm = (m == 0) ? WQ : (m == 1) ? WK : WV;
    const float4 w = *(const float4*)&Wm[(size_t)k * DD + d4];
    const float vals[4] = {w.x, w.y, w.z, w.w};
#pragma unroll
    for (int e = 0; e < 4; ++e) {
        const int n = m * 64 + d4 + e;               // concat col 0..191
        const float x = vals[e] * 1024.f;            // exact pow2 pre-scale
        const _Float16 h = (_Float16)x;
        const _Float16 l = (_Float16)(x - (float)h);
        const int off = (k >> 6) * WCH +
                        (((n >> 4) * 2 + ((k >> 5) & 1)) * 64 +
                         ((k >> 3) & 3) * 16 + (n & 15)) * 8 + (k & 7);
        Whg[off] = h;
        Wlg[off] = l;
    }
}

// ---------------------------------------------------------------------------
// Kernel 1: MFMA projection (fp16 split-3) + xPos epilogue.
// grid 256 blocks x 256 thr. Block = 32 rows x 192 cols. Wave w: rowtiles {0,1},
// coltiles 3w..3w+2. 16 K-chunks of 64 (2 MFMA ksteps each).
// LDS: Xh/Xl 4KB each + Wh/Wl 24KB each = 56 KB, fragment-ordered.
// ---------------------------------------------------------------------------
__global__ __launch_bounds__(256) void proj_mfma(
    const float* __restrict__ X, const _Float16* __restrict__ Whg,
    const _Float16* __restrict__ Wlg, float* __restrict__ Qx,
    float* __restrict__ Kx, float* __restrict__ Vx)
{
    __shared__ __align__(16) _Float16 lds[28672];
    _Float16* Xh = lds;             // 2048 halfs
    _Float16* Xl = lds + 2048;      // 2048
    _Float16* Wh = lds + 4096;      // 12288
    _Float16* Wl = lds + 16384;     // 12288

    const int tid  = threadIdx.x;
    const int wv   = tid >> 6;
    const int lane = tid & 63;
    const int r0   = blockIdx.x * 32;

    // staging coords
    const int xrow = tid >> 3;              // 0..31
    const int xk8  = (tid & 7) * 8;         // 0..56
    const int xslot = (((xrow >> 4) * 2 + (xk8 >> 5)) * 64 +
                       ((xk8 >> 3) & 3) * 16 + (xrow & 15)) * 8;

    f32x4 acc[6];
#pragma unroll
    for (int i = 0; i < 6; ++i) acc[i] = (f32x4){0.f, 0.f, 0.f, 0.f};

    float4 pxa, pxb;
    f16x8  pwh[6], pwl[6];
    {   // prefetch chunk 0
        const float* xp = &X[(size_t)(r0 + xrow) * HH + xk8];
        pxa = *(const float4*)&xp[0];
        pxb = *(const float4*)&xp[4];
#pragma unroll
        for (int i = 0; i < 6; ++i) {
            pwh[i] = *(const f16x8*)&Whg[(size_t)(tid + i * 256) * 8];
            pwl[i] = *(const f16x8*)&Wlg[(size_t)(tid + i * 256) * 8];
        }
    }

    for (int ch = 0; ch < 16; ++ch) {
        __syncthreads();
        // commit prefetched chunk
        {
            const float xv[8] = {pxa.x, pxa.y, pxa.z, pxa.w,
                                 pxb.x, pxb.y, pxb.z, pxb.w};
            f16x8 hv, lv;
#pragma unroll
            for (int e = 0; e < 8; ++e) {
                const _Float16 h = (_Float16)xv[e];
                hv[e] = h;
                lv[e] = (_Float16)(xv[e] - (float)h);
            }
            *(f16x8*)&Xh[xslot] = hv;
            *(f16x8*)&Xl[xslot] = lv;
#pragma unroll
            for (int i = 0; i < 6; ++i) {
                *(f16x8*)&Wh[(tid + i * 256) * 8] = pwh[i];
                *(f16x8*)&Wl[(tid + i * 256) * 8] = pwl[i];
            }
        }
        __syncthreads();
        // prefetch next chunk
        if (ch + 1 < 16) {
            const float* xp = &X[(size_t)(r0 + xrow) * HH + (ch + 1) * 64 + xk8];
            pxa = *(const float4*)&xp[0];
            pxb = *(const float4*)&xp[4];
            const size_t cb = (size_t)(ch + 1) * WCH;
#pragma unroll
            for (int i = 0; i < 6; ++i) {
                pwh[i] = *(const f16x8*)&Whg[cb + (size_t)(tid + i * 256) * 8];
                pwl[i] = *(const f16x8*)&Wlg[cb + (size_t)(tid + i * 256) * 8];
            }
        }
        // compute: 2 ksteps x (2 rowtiles x 3 coltiles x 3 split products)
#pragma unroll
        for (int kt = 0; kt < 2; ++kt) {
            const f16x8 a0h = *(const f16x8*)&Xh[((0 * 2 + kt) * 64 + lane) * 8];
            const f16x8 a0l = *(const f16x8*)&Xl[((0 * 2 + kt) * 64 + lane) * 8];
            const f16x8 a1h = *(const f16x8*)&Xh[((1 * 2 + kt) * 64 + lane) * 8];
            const f16x8 a1l = *(const f16x8*)&Xl[((1 * 2 + kt) * 64 + lane) * 8];
#pragma unroll
            for (int cj = 0; cj < 3; ++cj) {
                const int ctg = wv * 3 + cj;
                const f16x8 bh = *(const f16x8*)&Wh[((ctg * 2 + kt) * 64 + lane) * 8];
                const f16x8 bl = *(const f16x8*)&Wl[((ctg * 2 + kt) * 64 + lane) * 8];
                acc[cj] = __builtin_amdgcn_mfma_f32_16x16x32_f16(a0h, bh, acc[cj], 0, 0, 0);
                acc[cj] = __builtin_amdgcn_mfma_f32_16x16x32_f16(a0h, bl, acc[cj], 0, 0, 0);
                acc[cj] = __builtin_amdgcn_mfma_f32_16x16x32_f16(a0l, bh, acc[cj], 0, 0, 0);
                acc[3 + cj] = __builtin_amdgcn_mfma_f32_16x16x32_f16(a1h, bh, acc[3 + cj], 0, 0, 0);
                acc[3 + cj] = __builtin_amdgcn_mfma_f32_16x16x32_f16(a1h, bl, acc[3 + cj], 0, 0, 0);
                acc[3 + cj] = __builtin_amdgcn_mfma_f32_16x16x32_f16(a1l, bh, acc[3 + cj], 0, 0, 0);
            }
        }
    }

    // ---- epilogue: descale + xPos, C layout col=lane&15, row=quad*4+reg ----
    const int quad = lane >> 4;
    const int c16  = lane & 15;
#pragma unroll
    for (int rt = 0; rt < 2; ++rt) {
#pragma unroll
        for (int cj = 0; cj < 3; ++cj) {
            const int ctg = wv * 3 + cj;
            const f32x4 v = acc[rt * 3 + cj];
            const int col = ctg * 16 + c16;
            const int mat = ctg >> 2;            // 0=Q 1=K 2=V
            const int d   = col & 63;
            if (mat < 2) {
                const int i2 = d >> 1;
                const float sv   = (2.f * (float)i2 + 25.6f) / 89.6f;
                const float l2sv = log2f(sv);
                const float ifr  = exp2f(-13.28771237954945f * ((float)i2 / 32.f));
                const float sgn  = (mat == 0) ? 1.f : -1.f;
                float* dst = (mat == 0) ? Qx : Kx;
#pragma unroll
                for (int r = 0; r < 4; ++r) {
                    const int row = r0 + rt * 16 + quad * 4 + r;
                    const float val = v[r] * (1.f / 1024.f);
                    const float p = __shfl_xor(val, 1, 64);
                    const float pf = (float)(row & (LL - 1));
                    const float scl = exp2f(sgn * (pf * (1.f / 512.f)) * l2sv);
                    float s, c;
                    sincosf(pf * ifr, &s, &c);
                    s *= scl; c *= scl;
                    const float o = ((col & 1) == 0) ? val * c - p * s
                                                     : val * c + p * s;
                    dst[(size_t)row * DD + d] = o;
                }
            } else {
#pragma unroll
                for (int r = 0; r < 4; ++r) {
                    const int row = r0 + rt * 16 + quad * 4 + r;
                    Vx[(size_t)row * DD + d] = v[r] * (1.f / 1024.f);
                }
            }
        }
    }
}

// ---------------------------------------------------------------------------
// Kernel 2: per-chunk KV summary U[chunk][d][d'] = sum_j g^(63-j) K[j][d] V[j][d']
// grid 256 blocks = (chunk 128) x (dp-half 2), 256 threads.
// ---------------------------------------------------------------------------
__global__ __launch_bounds__(256) void chunk_kv(
    const float* __restrict__ Kx, const float* __restrict__ Vx,
    float* __restrict__ U)
{
    __shared__ float Kl[CHK][DD];     // weighted K, 16 KB
    __shared__ float Vl[CHK][32];     // V dp-slice, 8 KB
    const int tid   = threadIdx.x;
    const int bc    = blockIdx.x;
    const int chunk = bc >> 1;
    const int dph   = (bc & 1) * 32;
    const size_t base = (size_t)chunk * CHK * DD;
    const float l2g = log2f(GAMMA);
#pragma unroll
    for (int i = 0; i < 4; ++i) {
        const int f   = tid + i * 256;
        const int row = f >> 4;
        const int c4  = (f & 15) * 4;
        float4 kv = *(const float4*)&Kx[base + (size_t)row * DD + c4];
        const float w = exp2f((float)(CHK - 1 - row) * l2g);
        kv.x *= w; kv.y *= w; kv.z *= w; kv.w *= w;
        *(float4*)&Kl[row][c4] = kv;
    }
#pragma unroll
    for (int i = 0; i < 2; ++i) {
        const int f   = tid + i * 256;
        const int row = f >> 3;
        const int c4  = (f & 7) * 4;
        *(float4*)&Vl[row][c4] = *(const float4*)&Vx[base + (size_t)row * DD + dph + c4];
    }
    __syncthreads();
    const int dgr = tid >> 4;   // d-group: rows dgr*4..+3
    const int dc  = tid & 15;   // dp pair
    float a[4][2] = {{0,0},{0,0},{0,0},{0,0}};
#pragma unroll 8
    for (int j = 0; j < CHK; ++j) {
        const float4 kv = *(const float4*)&Kl[j][dgr * 4];
        const float2 vv = *(const float2*)&Vl[j][dc * 2];
        a[0][0] += kv.x * vv.x; a[0][1] += kv.x * vv.y;
        a[1][0] += kv.y * vv.x; a[1][1] += kv.y * vv.y;
        a[2][0] += kv.z * vv.x; a[2][1] += kv.z * vv.y;
        a[3][0] += kv.w * vv.x; a[3][1] += kv.w * vv.y;
    }
#pragma unroll
    for (int r = 0; r < 4; ++r) {
        *(float2*)&U[((size_t)chunk * DD + dgr * 4 + r) * DD + dph + dc * 2] =
            make_float2(a[r][0], a[r][1]);
    }
}

// ---------------------------------------------------------------------------
// Kernel 3: per-chunk output, T built on-the-fly from last 8 U chunks.
//   T_c = sum_{D=1..8} g64^(D-1) U[c-D]   (g64^8 ~ 8e-8: dropped terms invisible)
// grid 256 blocks = (chunk 128) x (n-half 2), 256 thr.
// ---------------------------------------------------------------------------
__global__ __launch_bounds__(256) void chunk_out(
    const float* __restrict__ Qx, const float* __restrict__ Kx,
    const float* __restrict__ Vx, const float* __restrict__ U,
    float* __restrict__ out)
{
    __shared__ __align__(16) float smA[6272];       // Ql:0..2175, Klt:2176..6271
    __shared__ __align__(16) float VTl[128 * 64];
    __shared__ float pwl[CHK + 1];
    const int tid   = threadIdx.x;
    const int bc    = blockIdx.x;
    const int chunk = bc >> 1;
    const int nh    = (bc & 1) * 32;
    const size_t base = (size_t)chunk * CHK * DD;

    if (tid <= CHK) pwl[tid] = exp2f((float)tid * log2f(GAMMA));

#pragma unroll
    for (int i = 0; i < 2; ++i) {                   // Ql rows nh..nh+31
        const int f   = tid + i * 256;
        const int row = f >> 4;
        const int c4  = (f & 15) * 4;
        *(float4*)&smA[row * 68 + c4] =
            *(const float4*)&Qx[base + (size_t)(nh + row) * DD + c4];
    }
#pragma unroll
    for (int i = 0; i < 4; ++i) {                   // Klt[k][m]
        const int f  = tid + i * 256;
        const int m  = f & 63;
        const int k4 = (f >> 6) * 4;
        const float4 kk = *(const float4*)&Kx[base + (size_t)m * DD + k4];
        smA[2176 + (k4 + 0) * 64 + m] = kk.x;
        smA[2176 + (k4 + 1) * 64 + m] = kk.y;
        smA[2176 + (k4 + 2) * 64 + m] = kk.z;
        smA[2176 + (k4 + 3) * 64 + m] = kk.w;
    }
#pragma unroll
    for (int i = 0; i < 4; ++i) {                   // VT rows 0..63 = V
        const int f   = tid + i * 256;
        const int row = f >> 4;
        const int c4  = (f & 15) * 4;
        *(float4*)&VTl[row * 64 + c4] =
            *(const float4*)&Vx[base + (size_t)row * DD + c4];
    }
    {                                               // VT rows 64..127 = T_c
        const int cloc = chunk & 63;
        const float g64 = exp2f(64.f * log2f(GAMMA));
#pragma unroll
        for (int i = 0; i < 4; ++i) {
            const int f   = tid + i * 256;
            const int row = f >> 4;                 // d
            const int c4  = (f & 15) * 4;
            float tx = 0.f, ty = 0.f, tz = 0.f, tw = 0.f;
            float w = 1.f;
            for (int dl = 1; dl <= 8; ++dl) {
                if (dl <= cloc) {
                    const float4 u = *(const float4*)
                        &U[((size_t)(chunk - dl) * DD + row) * DD + c4];
                    tx += w * u.x; ty += w * u.y; tz += w * u.z; tw += w * u.w;
                }
                w *= g64;
            }
            *(float4*)&VTl[(64 + row) * 64 + c4] = make_float4(tx, ty, tz, tw);
        }
    }
    __syncthreads();

    // ---- phase 1: scores, thread tile 2n x 4m ----
    const int ng = tid >> 4;
    const int mg = tid & 15;
    const int m0 = mg * 4;
    float sacc[2][4];
#pragma unroll
    for (int r = 0; r < 2; ++r)
#pragma unroll
        for (int j = 0; j < 4; ++j) sacc[r][j] = 0.f;

#pragma unroll 4
    for (int k4 = 0; k4 < 16; ++k4) {
        const float4 qv0 = *(const float4*)&smA[(ng * 2 + 0) * 68 + k4 * 4];
        const float4 qv1 = *(const float4*)&smA[(ng * 2 + 1) * 68 + k4 * 4];
#pragma unroll
        for (int u = 0; u < 4; ++u) {
            const float4 kv = *(const float4*)&smA[2176 + (k4 * 4 + u) * 64 + m0];
            const float x0 = (u == 0) ? qv0.x : (u == 1) ? qv0.y : (u == 2) ? qv0.z : qv0.w;
            const float x1 = (u == 0) ? qv1.x : (u == 1) ? qv1.y : (u == 2) ? qv1.z : qv1.w;
            sacc[0][0] += x0 * kv.x; sacc[0][1] += x0 * kv.y; sacc[0][2] += x0 * kv.z; sacc[0][3] += x0 * kv.w;
            sacc[1][0] += x1 * kv.x; sacc[1][1] += x1 * kv.y; sacc[1][2] += x1 * kv.z; sacc[1][3] += x1 * kv.w;
        }
    }
    const float4 qa0 = *(const float4*)&smA[(ng * 2 + 0) * 68 + m0];
    const float4 qa1 = *(const float4*)&smA[(ng * 2 + 1) * 68 + m0];
    __syncthreads();

#pragma unroll
    for (int r = 0; r < 2; ++r) {
        const int nl = ng * 2 + r;
        const int n  = nh + nl;
        float4 sv;
        sv.x = (n >= m0 + 0) ? sacc[r][0] * pwl[n - (m0 + 0)] : 0.f;
        sv.y = (n >= m0 + 1) ? sacc[r][1] * pwl[n - (m0 + 1)] : 0.f;
        sv.z = (n >= m0 + 2) ? sacc[r][2] * pwl[n - (m0 + 2)] : 0.f;
        sv.w = (n >= m0 + 3) ? sacc[r][3] * pwl[n - (m0 + 3)] : 0.f;
        *(float4*)&smA[nl * 132 + m0] = sv;
        const float w = pwl[n + 1];
        const float4 qa = r ? qa1 : qa0;
        *(float4*)&smA[nl * 132 + 64 + m0] =
            make_float4(qa.x * w, qa.y * w, qa.z * w, qa.w * w);
    }
    __syncthreads();

    // ---- phase 2: out = S2 @ VT, thread tile 2n x 4d' ----
    const int dg = tid & 15;
    float oacc[2][4];
#pragma unroll
    for (int r = 0; r < 2; ++r)
#pragma unroll
        for (int j = 0; j < 4; ++j) oacc[r][j] = 0.f;

#pragma unroll 4
    for (int m4 = 0; m4 < 32; ++m4) {
        const float4 s0 = *(const float4*)&smA[(ng * 2 + 0) * 132 + m4 * 4];
        const float4 s1 = *(const float4*)&smA[(ng * 2 + 1) * 132 + m4 * 4];
#pragma unroll
        for (int mm = 0; mm < 4; ++mm) {
            const float4 vv = *(const float4*)&VTl[(m4 * 4 + mm) * 64 + dg * 4];
            const float a0 = (mm == 0) ? s0.x : (mm == 1) ? s0.y : (mm == 2) ? s0.z : s0.w;
            const float a1 = (mm == 0) ? s1.x : (mm == 1) ? s1.y : (mm == 2) ? s1.z : s1.w;
            oacc[0][0] += a0 * vv.x; oacc[0][1] += a0 * vv.y; oacc[0][2] += a0 * vv.z; oacc[0][3] += a0 * vv.w;
            oacc[1][0] += a1 * vv.x; oacc[1][1] += a1 * vv.y; oacc[1][2] += a1 * vv.z; oacc[1][3] += a1 * vv.w;
        }
    }
#pragma unroll
    for (int r = 0; r < 2; ++r) {
        *(float4*)&out[base + (size_t)(nh + ng * 2 + r) * DD + dg * 4] =
            make_float4(oacc[r][0], oacc[r][1], oacc[r][2], oacc[r][3]);
    }
}

// ---------------------------------------------------------------------------
extern "C" void kernel_launch(void* const* d_in, const int* in_sizes, int n_in,
                              void* d_out, int out_size, void* d_ws, size_t ws_size,
                              hipStream_t stream)
{
    const float* X  = (const float*)d_in[0];
    const float* WQ = (const float*)d_in[1];
    const float* WK = (const float*)d_in[2];
    const float* WV = (const float*)d_in[3];
    float* out = (float*)d_out;

    float* ws = (float*)d_ws;
    float* Qx = ws;                                    // 524288 f
    float* Kx = Qx + (size_t)BLROWS * DD;              // 524288 f
    float* Vx = Kx + (size_t)BLROWS * DD;              // 524288 f
    float* U  = Vx + (size_t)BLROWS * DD;              // 524288 f
    _Float16* Whg = (_Float16*)(U + (size_t)NB * NCH * DD * DD);  // 196608 h
    _Float16* Wlg = Whg + 196608;                                  // 196608 h
    // total: 4*524288 floats + 2*196608 halfs = 9.2 MB

    hipLaunchKernelGGL(prep_w, dim3(192), dim3(256), 0, stream,
                       WQ, WK, WV, Whg, Wlg);
    hipLaunchKernelGGL(proj_mfma, dim3(BLROWS / 32), dim3(256), 0, stream,
                       X, Whg, Wlg, Qx, Kx, Vx);
    hipLaunchKernelGGL(chunk_kv, dim3(2 * NB * NCH), dim3(256), 0, stream, Kx, Vx, U);
    hipLaunchKernelGGL(chunk_out, dim3(2 * NB * NCH), dim3(256), 0, stream,
                       Qx, Kx, Vx, U, out);
}

// Round 4
// 116.903 us; speedup vs baseline: 1.3984x; 1.0631x over previous
//
#include <hip/hip_runtime.h>
#include <math.h>

#define NB 2
#define LL 4096
#define HH 1024
#define DD 64
#define CHK 64
#define NCH 64            /* LL/CHK */
#define BLROWS (NB*LL)    /* 8192 */
#define NCHT (NB*NCH)     /* 128 total chunks */
#define GAMMA 0.96875f

typedef _Float16 f16x8 __attribute__((ext_vector_type(8)));
typedef _Float16 f16x4 __attribute__((ext_vector_type(4)));
typedef float    f32x4 __attribute__((ext_vector_type(4)));

// W split layout: [16 kchunks][12 coltiles][2 ktiles][64 lanes][8 halfs]
#define WCH 12288

// ---------------------------------------------------------------------------
// Kernel 0: split W (scaled 2^10) into fp16 hi/lo, fragment order.
// Thread = one f16x8 output slot -> perfectly coalesced stores.
// grid 96 x 256 (24576 slots).
// ---------------------------------------------------------------------------
__global__ __launch_bounds__(256) void prep_w(
    const float* __restrict__ WQ, const float* __restrict__ WK,
    const float* __restrict__ WV, _Float16* __restrict__ Whg,
    _Float16* __restrict__ Wlg)
{
    const unsigned t = blockIdx.x * 256 + threadIdx.x;   // 0..24575
    const unsigned kchunk = t / 1536u;
    const unsigned s = t - kchunk * 1536u;
    const int ct2  = s >> 6;            // (n16)*2 + kt
    const int lane = s & 63;
    const int n16  = ct2 >> 1;
    const int kt   = ct2 & 1;
    const int quad = lane >> 4;
    const int n    = n16 * 16 + (lane & 15);
    const int k0   = (int)kchunk * 64 + kt * 32 + quad * 8;
    const int m    = n >> 6;
    const int d    = n & 63;
    const float* Wm = (m == 0) ? WQ : (m == 1) ? WK : WV;
    f16x8 hv, lv;
#pragma unroll
    for (int j = 0; j < 8; ++j) {
        const float x = Wm[(size_t)(k0 + j) * DD + d] * 1024.f;
        const _Float16 h = (_Float16)x;
        hv[j] = h;
        lv[j] = (_Float16)(x - (float)h);
    }
    *(f16x8*)&Whg[(size_t)t * 8] = hv;
    *(f16x8*)&Wlg[(size_t)t * 8] = lv;
}

// ---------------------------------------------------------------------------
// Kernel 1: MFMA projection (fp16 split-3) + xPos epilogue, renormalized
// per chunk (scale exponent uses pos&63) -> Q~,K~,V stored fp16 row-major.
// grid 256 x 256. Block = 32 rows x 192 cols.
// ---------------------------------------------------------------------------
__global__ __launch_bounds__(256) void proj_mfma(
    const float* __restrict__ X, const _Float16* __restrict__ Whg,
    const _Float16* __restrict__ Wlg, _Float16* __restrict__ Qr,
    _Float16* __restrict__ Kr, _Float16* __restrict__ Vr)
{
    __shared__ __align__(16) _Float16 lds[28672];
    _Float16* Xh = lds;             // 2048 halfs
    _Float16* Xl = lds + 2048;      // 2048
    _Float16* Wh = lds + 4096;      // 12288
    _Float16* Wl = lds + 16384;     // 12288

    const int tid  = threadIdx.x;
    const int wv   = tid >> 6;
    const int lane = tid & 63;
    const int r0   = blockIdx.x * 32;

    const int xrow = tid >> 3;              // 0..31
    const int xk8  = (tid & 7) * 8;         // 0..56
    const int xslot = (((xrow >> 4) * 2 + (xk8 >> 5)) * 64 +
                       ((xk8 >> 3) & 3) * 16 + (xrow & 15)) * 8;

    f32x4 acc[6];
#pragma unroll
    for (int i = 0; i < 6; ++i) acc[i] = (f32x4){0.f, 0.f, 0.f, 0.f};

    float4 pxa, pxb;
    f16x8  pwh[6], pwl[6];
    {
        const float* xp = &X[(size_t)(r0 + xrow) * HH + xk8];
        pxa = *(const float4*)&xp[0];
        pxb = *(const float4*)&xp[4];
#pragma unroll
        for (int i = 0; i < 6; ++i) {
            pwh[i] = *(const f16x8*)&Whg[(size_t)(tid + i * 256) * 8];
            pwl[i] = *(const f16x8*)&Wlg[(size_t)(tid + i * 256) * 8];
        }
    }

    for (int ch = 0; ch < 16; ++ch) {
        __syncthreads();
        {
            const float xv[8] = {pxa.x, pxa.y, pxa.z, pxa.w,
                                 pxb.x, pxb.y, pxb.z, pxb.w};
            f16x8 hv, lv;
#pragma unroll
            for (int e = 0; e < 8; ++e) {
                const _Float16 h = (_Float16)xv[e];
                hv[e] = h;
                lv[e] = (_Float16)(xv[e] - (float)h);
            }
            *(f16x8*)&Xh[xslot] = hv;
            *(f16x8*)&Xl[xslot] = lv;
#pragma unroll
            for (int i = 0; i < 6; ++i) {
                *(f16x8*)&Wh[(tid + i * 256) * 8] = pwh[i];
                *(f16x8*)&Wl[(tid + i * 256) * 8] = pwl[i];
            }
        }
        __syncthreads();
        if (ch + 1 < 16) {
            const float* xp = &X[(size_t)(r0 + xrow) * HH + (ch + 1) * 64 + xk8];
            pxa = *(const float4*)&xp[0];
            pxb = *(const float4*)&xp[4];
            const size_t cb = (size_t)(ch + 1) * WCH;
#pragma unroll
            for (int i = 0; i < 6; ++i) {
                pwh[i] = *(const f16x8*)&Whg[cb + (size_t)(tid + i * 256) * 8];
                pwl[i] = *(const f16x8*)&Wlg[cb + (size_t)(tid + i * 256) * 8];
            }
        }
#pragma unroll
        for (int kt = 0; kt < 2; ++kt) {
            const f16x8 a0h = *(const f16x8*)&Xh[((0 * 2 + kt) * 64 + lane) * 8];
            const f16x8 a0l = *(const f16x8*)&Xl[((0 * 2 + kt) * 64 + lane) * 8];
            const f16x8 a1h = *(const f16x8*)&Xh[((1 * 2 + kt) * 64 + lane) * 8];
            const f16x8 a1l = *(const f16x8*)&Xl[((1 * 2 + kt) * 64 + lane) * 8];
#pragma unroll
            for (int cj = 0; cj < 3; ++cj) {
                const int ctg = wv * 3 + cj;
                const f16x8 bh = *(const f16x8*)&Wh[((ctg * 2 + kt) * 64 + lane) * 8];
                const f16x8 bl = *(const f16x8*)&Wl[((ctg * 2 + kt) * 64 + lane) * 8];
                acc[cj] = __builtin_amdgcn_mfma_f32_16x16x32_f16(a0h, bh, acc[cj], 0, 0, 0);
                acc[cj] = __builtin_amdgcn_mfma_f32_16x16x32_f16(a0h, bl, acc[cj], 0, 0, 0);
                acc[cj] = __builtin_amdgcn_mfma_f32_16x16x32_f16(a0l, bh, acc[cj], 0, 0, 0);
                acc[3 + cj] = __builtin_amdgcn_mfma_f32_16x16x32_f16(a1h, bh, acc[3 + cj], 0, 0, 0);
                acc[3 + cj] = __builtin_amdgcn_mfma_f32_16x16x32_f16(a1h, bl, acc[3 + cj], 0, 0, 0);
                acc[3 + cj] = __builtin_amdgcn_mfma_f32_16x16x32_f16(a1l, bh, acc[3 + cj], 0, 0, 0);
            }
        }
    }

    // epilogue: descale + xPos with per-chunk renormalized scale, fp16 out.
    const int quad = lane >> 4;
    const int c16  = lane & 15;
#pragma unroll
    for (int rt = 0; rt < 2; ++rt) {
#pragma unroll
        for (int cj = 0; cj < 3; ++cj) {
            const int ctg = wv * 3 + cj;
            const f32x4 v = acc[rt * 3 + cj];
            const int col = ctg * 16 + c16;
            const int mat = ctg >> 2;            // 0=Q 1=K 2=V
            const int d   = col & 63;
            if (mat < 2) {
                const int i2 = d >> 1;
                const float sv   = (2.f * (float)i2 + 25.6f) / 89.6f;
                const float l2sv = log2f(sv);
                const float ifr  = exp2f(-13.28771237954945f * ((float)i2 / 32.f));
                const float sgn  = (mat == 0) ? 1.f : -1.f;
                _Float16* dst = (mat == 0) ? Qr : Kr;
#pragma unroll
                for (int r = 0; r < 4; ++r) {
                    const int row = r0 + rt * 16 + quad * 4 + r;
                    const float val = v[r] * (1.f / 1024.f);
                    const float p = __shfl_xor(val, 1, 64);
                    const float pf  = (float)(row & (LL - 1));   // abs pos: sin/cos
                    const float pfs = (float)(row & 63);          // renorm: scale
                    const float scl = exp2f(sgn * (pfs * (1.f / 512.f)) * l2sv);
                    float s, c;
                    sincosf(pf * ifr, &s, &c);
                    s *= scl; c *= scl;
                    const float o = ((col & 1) == 0) ? val * c - p * s
                                                     : val * c + p * s;
                    dst[(size_t)row * DD + d] = (_Float16)o;
                }
            } else {
#pragma unroll
                for (int r = 0; r < 4; ++r) {
                    const int row = r0 + rt * 16 + quad * 4 + r;
                    Vr[(size_t)row * DD + d] = (_Float16)(v[r] * (1.f / 1024.f));
                }
            }
        }
    }
}

// ---------------------------------------------------------------------------
// Kernel 2: U~[chunk][d][d'] = sum_j g^(63-j) K~[j][d] V[j][d']  (fp32 out)
// grid 256 = (chunk 128) x (d'-half 2), 256 thr.
// ---------------------------------------------------------------------------
__global__ __launch_bounds__(256) void chunk_kv(
    const _Float16* __restrict__ Kr, const _Float16* __restrict__ Vr,
    float* __restrict__ U)
{
    __shared__ _Float16 Kl[64 * 64];
    __shared__ _Float16 Vl[64 * 32];
    __shared__ float pwd[64];
    const int tid   = threadIdx.x;
    const int bc    = blockIdx.x;
    const int chunk = bc >> 1;
    const int dph   = (bc & 1) * 32;
    const size_t rbase = (size_t)chunk * CHK * DD;
    const float l2g = log2f(GAMMA);

    if (tid < 64) pwd[tid] = exp2f((float)(63 - tid) * l2g);
    {
        const int row = tid >> 2;
        const int c0  = (tid & 3) * 16;
        *(f16x8*)&Kl[row * 64 + c0]     = *(const f16x8*)&Kr[rbase + (size_t)row * DD + c0];
        *(f16x8*)&Kl[row * 64 + c0 + 8] = *(const f16x8*)&Kr[rbase + (size_t)row * DD + c0 + 8];
        const int c1 = (tid & 3) * 8;
        *(f16x8*)&Vl[row * 32 + c1] = *(const f16x8*)&Vr[rbase + (size_t)row * DD + dph + c1];
    }
    __syncthreads();
    const int dgr = tid >> 4;   // d rows dgr*4..+3
    const int dc  = tid & 15;   // d' pair
    float a[4][2] = {{0,0},{0,0},{0,0},{0,0}};
#pragma unroll 8
    for (int j = 0; j < CHK; ++j) {
        const f16x4 kh = *(const f16x4*)&Kl[j * 64 + dgr * 4];
        const float w  = pwd[j];
        const float v0 = (float)Vl[j * 32 + dc * 2]     * w;
        const float v1 = (float)Vl[j * 32 + dc * 2 + 1] * w;
        const float k0 = (float)kh[0], k1 = (float)kh[1];
        const float k2 = (float)kh[2], k3 = (float)kh[3];
        a[0][0] += k0 * v0; a[0][1] += k0 * v1;
        a[1][0] += k1 * v0; a[1][1] += k1 * v1;
        a[2][0] += k2 * v0; a[2][1] += k2 * v1;
        a[3][0] += k3 * v0; a[3][1] += k3 * v1;
    }
#pragma unroll
    for (int r = 0; r < 4; ++r) {
        *(float2*)&U[((size_t)chunk * DD + dgr * 4 + r) * DD + dph + dc * 2] =
            make_float2(a[r][0], a[r][1]);
    }
}

// ---------------------------------------------------------------------------
// Kernel 3: build T~_c = sum_{D=1..8} g^{64(D-1)} sv_d^{D/8} U~[c-D]  and emit
// [V ; T~] in phase-B fragment order, fp16.  grid 128 blocks x 256 thr.
// Frag element (mrow,d') at ((nt*4+ks)*64 + 16*((mrow&31)>>3) + (d'&15))*8 + (mrow&7)
// ---------------------------------------------------------------------------
__global__ __launch_bounds__(256) void prep_vt(
    const _Float16* __restrict__ Vr, const float* __restrict__ U,
    _Float16* __restrict__ VTf)
{
    __shared__ float    Tl[64 * 68];
    __shared__ _Float16 Vl[64 * 72];
    const int tid   = threadIdx.x;
    const int chunk = blockIdx.x;
    const int cloc  = chunk & 63;
    const size_t rbase = (size_t)chunk * CHK * DD;
    const float l2g = log2f(GAMMA);

    {   // stage V rows
        const int row = tid >> 2;
        const int c0  = (tid & 3) * 16;
        *(f16x8*)&Vl[row * 72 + c0]     = *(const f16x8*)&Vr[rbase + (size_t)row * DD + c0];
        *(f16x8*)&Vl[row * 72 + c0 + 8] = *(const f16x8*)&Vr[rbase + (size_t)row * DD + c0 + 8];
    }
    {   // T~ build: thread = (d = tid>>2, 16 d' starting (tid&3)*16)
        const int d  = tid >> 2;
        const int dq = (tid & 3) * 16;
        const float sv = (2.f * (float)(d >> 1) + 25.6f) / 89.6f;
        const float l2sv = log2f(sv);
        float acc[16];
#pragma unroll
        for (int i = 0; i < 16; ++i) acc[i] = 0.f;
        for (int dl = 1; dl <= 8; ++dl) {
            if (dl <= cloc) {
                const float f = exp2f(64.f * (float)(dl - 1) * l2g +
                                      0.125f * (float)dl * l2sv);
                const float* up = &U[((size_t)(chunk - dl) * DD + d) * DD + dq];
#pragma unroll
                for (int i4 = 0; i4 < 4; ++i4) {
                    const float4 u = *(const float4*)&up[i4 * 4];
                    acc[i4 * 4 + 0] += f * u.x; acc[i4 * 4 + 1] += f * u.y;
                    acc[i4 * 4 + 2] += f * u.z; acc[i4 * 4 + 3] += f * u.w;
                }
            }
        }
#pragma unroll
        for (int i = 0; i < 16; ++i) Tl[d * 68 + dq + i] = acc[i];
    }
    __syncthreads();
    // frag emission: 1024 slots, 4 per thread
#pragma unroll
    for (int it = 0; it < 4; ++it) {
        const int s    = tid + it * 256;
        const int nt   = s >> 8;
        const int ks   = (s >> 6) & 3;
        const int lane = s & 63;
        const int quad = lane >> 4;
        const int dp   = nt * 16 + (lane & 15);
        const int mb   = ks * 32 + quad * 8;
        f16x8 v;
#pragma unroll
        for (int j = 0; j < 8; ++j) {
            const int mrow = mb + j;
            v[j] = (mrow < 64) ? Vl[mrow * 72 + dp]
                               : (_Float16)Tl[(mrow - 64) * 68 + dp];
        }
        *(f16x8*)&VTf[(size_t)chunk * 8192 + (size_t)s * 8] = v;
    }
}

// ---------------------------------------------------------------------------
// Kernel 4: chunk output, all-MFMA, no input LDS staging.
//   phase A: S = mask(Q~ K~^T)  (A-frags from Qr, B-frags = Kr row-major)
//   S2 = [S | g^{n'+1} Q~] -> LDS (A-frag order)
//   phase B: out = S2 @ [V;T~]  (B-frags from VTf)
// grid 256 = (chunk 128) x (n-half 2), 256 thr (4 waves).
// ---------------------------------------------------------------------------
__global__ __launch_bounds__(256) void chunk_out(
    const _Float16* __restrict__ Qr, const _Float16* __restrict__ Kr,
    const _Float16* __restrict__ VTf, float* __restrict__ out)
{
    __shared__ _Float16 Sb[32 * 136];
    __shared__ float pwl[65];
    const int tid   = threadIdx.x;
    const int bc    = blockIdx.x;
    const int chunk = bc >> 1;
    const int nh    = (bc & 1) * 32;
    const int w     = tid >> 6;
    const int lane  = tid & 63;
    const int quad  = lane >> 4;
    const int l15   = lane & 15;
    const int mtile = w >> 1;
    const int npair = (w & 1) * 2;
    const size_t rowbase = (size_t)chunk * CHK + nh;

    if (tid < 65) pwl[tid] = exp2f((float)tid * log2f(GAMMA));

    // A-frags (Q~) and phase-A B-frags (K~ row-major)
    f16x8 aQ[2], bK[2][2];
#pragma unroll
    for (int ks = 0; ks < 2; ++ks)
        aQ[ks] = *(const f16x8*)&Qr[(rowbase + mtile * 16 + l15) * DD +
                                    ks * 32 + quad * 8];
#pragma unroll
    for (int nt = 0; nt < 2; ++nt)
#pragma unroll
        for (int ks = 0; ks < 2; ++ks)
            bK[nt][ks] = *(const f16x8*)&Kr[((size_t)chunk * CHK +
                                            (npair + nt) * 16 + l15) * DD +
                                            ks * 32 + quad * 8];
    __syncthreads();   // pwl ready

    f32x4 sA[2] = {(f32x4){0.f,0.f,0.f,0.f}, (f32x4){0.f,0.f,0.f,0.f}};
#pragma unroll
    for (int nt = 0; nt < 2; ++nt)
#pragma unroll
        for (int ks = 0; ks < 2; ++ks)
            sA[nt] = __builtin_amdgcn_mfma_f32_16x16x32_f16(aQ[ks], bK[nt][ks],
                                                            sA[nt], 0, 0, 0);
    // mask + decay, write S (fp16) to Sb in A-layout
#pragma unroll
    for (int nt = 0; nt < 2; ++nt) {
        const int m = (npair + nt) * 16 + l15;
#pragma unroll
        for (int r = 0; r < 4; ++r) {
            const int nl = mtile * 16 + quad * 4 + r;   // local row 0..31
            const int n64 = nh + nl;
            const float val = (n64 >= m) ? sA[nt][r] * pwl[n64 - m] : 0.f;
            Sb[nl * 136 + m] = (_Float16)val;
        }
    }
    // Q'' columns 64..127 (even waves only)
    if ((w & 1) == 0) {
        const float g = pwl[nh + mtile * 16 + l15 + 1];
#pragma unroll
        for (int ks = 0; ks < 2; ++ks) {
            f16x8 qv;
#pragma unroll
            for (int j = 0; j < 8; ++j)
                qv[j] = (_Float16)((float)aQ[ks][j] * g);
            *(f16x8*)&Sb[(mtile * 16 + l15) * 136 + 64 + ks * 32 + quad * 8] = qv;
        }
    }
    __syncthreads();

    // phase B
    f32x4 oA[2] = {(f32x4){0.f,0.f,0.f,0.f}, (f32x4){0.f,0.f,0.f,0.f}};
#pragma unroll
    for (int ks = 0; ks < 4; ++ks) {
        const f16x8 aS = *(const f16x8*)&Sb[(mtile * 16 + l15) * 136 +
                                            ks * 32 + quad * 8];
#pragma unroll
        for (int nt = 0; nt < 2; ++nt) {
            const f16x8 bV = *(const f16x8*)&VTf[(size_t)chunk * 8192 +
                (size_t)((((npair + nt) * 4 + ks) * 64 + lane)) * 8];
            oA[nt] = __builtin_amdgcn_mfma_f32_16x16x32_f16(aS, bV, oA[nt], 0, 0, 0);
        }
    }
#pragma unroll
    for (int nt = 0; nt < 2; ++nt)
#pragma unroll
        for (int r = 0; r < 4; ++r)
            out[(rowbase + mtile * 16 + quad * 4 + r) * DD +
                (npair + nt) * 16 + l15] = oA[nt][r];
}

// ---------------------------------------------------------------------------
extern "C" void kernel_launch(void* const* d_in, const int* in_sizes, int n_in,
                              void* d_out, int out_size, void* d_ws, size_t ws_size,
                              hipStream_t stream)
{
    const float* X  = (const float*)d_in[0];
    const float* WQ = (const float*)d_in[1];
    const float* WK = (const float*)d_in[2];
    const float* WV = (const float*)d_in[3];
    float* out = (float*)d_out;

    _Float16* Whg = (_Float16*)d_ws;                 // 196608 h
    _Float16* Wlg = Whg + 196608;                    // 196608 h
    _Float16* Qr  = Wlg + 196608;                    // 524288 h
    _Float16* Kr  = Qr + (size_t)BLROWS * DD;        // 524288 h
    _Float16* Vr  = Kr + (size_t)BLROWS * DD;        // 524288 h
    _Float16* VTf = Vr + (size_t)BLROWS * DD;        // 1048576 h
    float*    U   = (float*)(VTf + (size_t)NCHT * 8192);  // 524288 f
    // total ~8.1 MB

    hipLaunchKernelGGL(prep_w, dim3(96), dim3(256), 0, stream,
                       WQ, WK, WV, Whg, Wlg);
    hipLaunchKernelGGL(proj_mfma, dim3(BLROWS / 32), dim3(256), 0, stream,
                       X, Whg, Wlg, Qr, Kr, Vr);
    hipLaunchKernelGGL(chunk_kv, dim3(2 * NCHT), dim3(256), 0, stream, Kr, Vr, U);
    hipLaunchKernelGGL(prep_vt, dim3(NCHT), dim3(256), 0, stream, Vr, U, VTf);
    hipLaunchKernelGGL(chunk_out, dim3(2 * NCHT), dim3(256), 0, stream,
                       Qr, Kr, VTf, out);
}